// Round 1
// baseline (493.140 us; speedup 1.0000x reference)
//
#include <hip/hip_runtime.h>

#define N_NODES 40000
#define N_EDGES 640000
#define CH 128
#define BN_EPS 1e-5f

// ws layout (bytes):
//   h:    [0, 20480000)            40000*128 float
//   dinv: [20480000, 20640000)     40000 float (deg, then rsqrt in place)
//   sums: [20640000, 20641024)     sum[128], sumsq[128]

__global__ __launch_bounds__(256) void zero_kernel(float* __restrict__ p, int n) {
    int i = blockIdx.x * blockDim.x + threadIdx.x;
    if (i < n) p[i] = 0.0f;
}

__global__ __launch_bounds__(256) void deg_kernel(const int* __restrict__ dst,
                                                  float* __restrict__ deg) {
    int e = blockIdx.x * blockDim.x + threadIdx.x;
    if (e < N_EDGES) atomicAdd(&deg[dst[e]], 1.0f);
}

__global__ __launch_bounds__(256) void dinv_kernel(float* __restrict__ deg) {
    int i = blockIdx.x * blockDim.x + threadIdx.x;
    if (i < N_NODES) deg[i] = rsqrtf(deg[i] + 1.0f);
}

#define ROWS_PER_BLOCK 16
__global__ __launch_bounds__(256) void matmul_kernel(const float* __restrict__ x,
                                                     const float* __restrict__ W,
                                                     float* __restrict__ h) {
    __shared__ float Ws[CH * CH];               // 64 KB
    __shared__ float xs[ROWS_PER_BLOCK][CH];    // 8 KB
    int t = threadIdx.x;
    for (int i = t; i < CH * CH / 4; i += 256)
        ((float4*)Ws)[i] = ((const float4*)W)[i];
    int row0 = blockIdx.x * ROWS_PER_BLOCK;
    for (int i = t; i < ROWS_PER_BLOCK * CH / 4; i += 256)
        ((float4*)xs)[i] = ((const float4*)(x + (size_t)row0 * CH))[i];
    __syncthreads();
    int ch = t & (CH - 1);
    int rh = t >> 7;  // 0 or 1
    for (int r = rh; r < ROWS_PER_BLOCK; r += 2) {
        float acc = 0.0f;
#pragma unroll 8
        for (int k = 0; k < CH; ++k)
            acc += xs[r][k] * Ws[k * CH + ch];
        h[(size_t)(row0 + r) * CH + ch] = acc;
    }
}

__global__ __launch_bounds__(256) void init_out_kernel(const float* __restrict__ h,
                                                       const float* __restrict__ dinv,
                                                       const float* __restrict__ b,
                                                       float* __restrict__ out) {
    int i = blockIdx.x * blockDim.x + threadIdx.x;  // float4 index
    if (i >= N_NODES * CH / 4) return;
    int row = i >> 5;       // 32 float4 per row
    int c4 = i & 31;
    float d = dinv[row];
    float s = d * d;
    float4 hv = ((const float4*)h)[i];
    float4 bv = ((const float4*)b)[c4];
    float4 o;
    o.x = hv.x * s + bv.x;
    o.y = hv.y * s + bv.y;
    o.z = hv.z * s + bv.z;
    o.w = hv.w * s + bv.w;
    ((float4*)out)[i] = o;
}

// one wave (64 lanes) per edge; lanes cover 128 channels in 2 steps
__global__ __launch_bounds__(256) void scatter_kernel(const int* __restrict__ src,
                                                      const int* __restrict__ dst,
                                                      const float* __restrict__ h,
                                                      const float* __restrict__ dinv,
                                                      float* __restrict__ out) {
    int wave = (blockIdx.x * blockDim.x + threadIdx.x) >> 6;
    int lane = threadIdx.x & 63;
    if (wave >= N_EDGES) return;
    int s = src[wave];
    int d = dst[wave];
    float norm = dinv[s] * dinv[d];
    const float* hs = h + (size_t)s * CH;
    float* od = out + (size_t)d * CH;
    atomicAdd(&od[lane], hs[lane] * norm);
    atomicAdd(&od[lane + 64], hs[lane + 64] * norm);
}

#define STAT_BLOCKS 256
__global__ __launch_bounds__(256) void bn_stats_kernel(const float* __restrict__ out,
                                                       float* __restrict__ sums) {
    int t = threadIdx.x;
    int ch = t & (CH - 1);
    int half = t >> 7;  // 0 or 1
    float s = 0.0f, sq = 0.0f;
    for (int row = blockIdx.x * 2 + half; row < N_NODES; row += gridDim.x * 2) {
        float v = out[(size_t)row * CH + ch];
        s += v;
        sq += v * v;
    }
    __shared__ float ls[256], lq[256];
    ls[t] = s;
    lq[t] = sq;
    __syncthreads();
    if (half == 0) {
        s += ls[t + 128];
        sq += lq[t + 128];
        atomicAdd(&sums[ch], s);
        atomicAdd(&sums[CH + ch], sq);
    }
}

__global__ __launch_bounds__(256) void bn_relu_kernel(float* __restrict__ out,
                                                      const float* __restrict__ sums,
                                                      const float* __restrict__ gamma,
                                                      const float* __restrict__ beta) {
    int i = blockIdx.x * blockDim.x + threadIdx.x;  // float4 index
    if (i >= N_NODES * CH / 4) return;
    int c0 = (i & 31) * 4;
    const float invN = 1.0f / (float)N_NODES;
    float4 v = ((float4*)out)[i];
    float r[4] = {v.x, v.y, v.z, v.w};
#pragma unroll
    for (int j = 0; j < 4; ++j) {
        int c = c0 + j;
        float mean = sums[c] * invN;
        float var = sums[CH + c] * invN - mean * mean;
        float scale = gamma[c] * rsqrtf(var + BN_EPS);
        float val = (r[j] - mean) * scale + beta[c];
        r[j] = val > 0.0f ? val : 0.0f;
    }
    v.x = r[0]; v.y = r[1]; v.z = r[2]; v.w = r[3];
    ((float4*)out)[i] = v;
}

extern "C" void kernel_launch(void* const* d_in, const int* in_sizes, int n_in,
                              void* d_out, int out_size, void* d_ws, size_t ws_size,
                              hipStream_t stream) {
    const float* x = (const float*)d_in[0];
    const int* ei = (const int*)d_in[1];
    const float* W = (const float*)d_in[2];
    const float* b = (const float*)d_in[3];
    const float* gamma = (const float*)d_in[4];
    const float* beta = (const float*)d_in[5];
    float* out = (float*)d_out;

    char* ws = (char*)d_ws;
    float* h = (float*)ws;
    float* dinv = (float*)(ws + 20480000);
    float* sums = (float*)(ws + 20640000);  // contiguous after dinv

    const int* src = ei;
    const int* dst = ei + N_EDGES;

    // zero deg (40000) + sums (256) in one contiguous pass: 40256 floats
    zero_kernel<<<(40256 + 255) / 256, 256, 0, stream>>>(dinv, 40256);
    deg_kernel<<<(N_EDGES + 255) / 256, 256, 0, stream>>>(dst, dinv);
    dinv_kernel<<<(N_NODES + 255) / 256, 256, 0, stream>>>(dinv);
    matmul_kernel<<<N_NODES / ROWS_PER_BLOCK, 256, 0, stream>>>(x, W, h);
    init_out_kernel<<<(N_NODES * CH / 4 + 255) / 256, 256, 0, stream>>>(h, dinv, b, out);
    scatter_kernel<<<(N_EDGES * 64) / 256, 256, 0, stream>>>(src, dst, h, dinv, out);
    bn_stats_kernel<<<STAT_BLOCKS, 256, 0, stream>>>(out, sums);
    bn_relu_kernel<<<(N_NODES * CH / 4 + 255) / 256, 256, 0, stream>>>(out, sums, gamma, beta);
}

// Round 2
// 282.874 us; speedup vs baseline: 1.7433x; 1.7433x over previous
//
#include <hip/hip_runtime.h>

#define N_NODES 40000
#define N_EDGES 640000
#define CH 128
#define BN_EPS 1e-5f
#define NBLK_SCAN 157  // ceil(40000/256)

// ---------- fast-path ws layout (bytes) ----------
//  h:        [0, 20480000)            40000*128 f32
//  deg:      [20480000, 20640000)     40000 i32
//  sums:     [20640000, 20641024)     256 f32  (contiguous after deg for one-shot zero)
//  offs:     [20641024, 20801024)     40000 i32
//  dinv:     [20801024, 20961024)     40000 f32
//  bases:    [20961024, 20961664)     157 i32 (padded)
//  csr:      [20961664, 23521664)     640000 i32
#define FAST_WS_BYTES 23521664ull

__global__ __launch_bounds__(256) void zero_kernel(int* __restrict__ p, int n) {
    int i = blockIdx.x * blockDim.x + threadIdx.x;
    if (i < n) p[i] = 0;
}

__global__ __launch_bounds__(256) void deg_kernel(const int* __restrict__ dst,
                                                  int* __restrict__ deg) {
    int e = blockIdx.x * blockDim.x + threadIdx.x;
    if (e < N_EDGES) atomicAdd(&deg[dst[e]], 1);
}

__global__ __launch_bounds__(256) void dinv_kernel(const int* __restrict__ deg,
                                                   float* __restrict__ dinv) {
    int i = blockIdx.x * blockDim.x + threadIdx.x;
    if (i < N_NODES) dinv[i] = rsqrtf((float)deg[i] + 1.0f);
}

// per-block exclusive scan of deg -> offs (block-local), block totals -> bases[]
__global__ __launch_bounds__(256) void scan_a(const int* __restrict__ deg,
                                              int* __restrict__ offs,
                                              int* __restrict__ bases) {
    __shared__ int tmp[256];
    int g = blockIdx.x * 256 + threadIdx.x;
    int v = (g < N_NODES) ? deg[g] : 0;
    tmp[threadIdx.x] = v;
    __syncthreads();
    for (int off = 1; off < 256; off <<= 1) {
        int t = (threadIdx.x >= off) ? tmp[threadIdx.x - off] : 0;
        __syncthreads();
        tmp[threadIdx.x] += t;
        __syncthreads();
    }
    if (g < N_NODES) offs[g] = tmp[threadIdx.x] - v;  // local exclusive
    if (threadIdx.x == 255) bases[blockIdx.x] = tmp[255];
}

// exclusive scan of the 157 block totals, in place
__global__ __launch_bounds__(256) void scan_b(int* __restrict__ bases) {
    __shared__ int tmp[256];
    int v = (threadIdx.x < NBLK_SCAN) ? bases[threadIdx.x] : 0;
    tmp[threadIdx.x] = v;
    __syncthreads();
    for (int off = 1; off < 256; off <<= 1) {
        int t = (threadIdx.x >= off) ? tmp[threadIdx.x - off] : 0;
        __syncthreads();
        tmp[threadIdx.x] += t;
        __syncthreads();
    }
    if (threadIdx.x < NBLK_SCAN) bases[threadIdx.x] = tmp[threadIdx.x] - v;
}

// bucket fill: pos = global_start(d) + bump; leaves offs[d] = local_excl+deg
__global__ __launch_bounds__(256) void fill_kernel(const int* __restrict__ src,
                                                   const int* __restrict__ dst,
                                                   const int* __restrict__ bases,
                                                   int* __restrict__ offs,
                                                   int* __restrict__ csr) {
    int e = blockIdx.x * blockDim.x + threadIdx.x;
    if (e >= N_EDGES) return;
    int d = dst[e];
    int pos = bases[d >> 8] + atomicAdd(&offs[d], 1);
    csr[pos] = src[e];
}

// x @ W: 32 rows/block, per-thread 4 ch (float4) x 4 rows
#define MM_ROWS 32
__global__ __launch_bounds__(256) void matmul_kernel(const float* __restrict__ x,
                                                     const float* __restrict__ W,
                                                     float* __restrict__ h) {
    __shared__ float Ws[CH * CH];        // 64 KB
    __shared__ float xs[MM_ROWS][CH];    // 16 KB
    int t = threadIdx.x;
    for (int i = t; i < CH * CH / 4; i += 256)
        ((float4*)Ws)[i] = ((const float4*)W)[i];
    size_t row0 = (size_t)blockIdx.x * MM_ROWS;
    for (int i = t; i < MM_ROWS * CH / 4; i += 256)
        ((float4*)xs)[i] = ((const float4*)(x + row0 * CH))[i];
    __syncthreads();
    int ch4 = t & 31;   // float4 column index
    int rg = t >> 5;    // row group [0,8)
    float4 acc0 = {0,0,0,0}, acc1 = {0,0,0,0}, acc2 = {0,0,0,0}, acc3 = {0,0,0,0};
#pragma unroll 4
    for (int k = 0; k < CH; ++k) {
        float4 wv = ((const float4*)Ws)[k * 32 + ch4];
        float x0 = xs[rg][k];
        float x1 = xs[rg + 8][k];
        float x2 = xs[rg + 16][k];
        float x3 = xs[rg + 24][k];
        acc0.x += x0 * wv.x; acc0.y += x0 * wv.y; acc0.z += x0 * wv.z; acc0.w += x0 * wv.w;
        acc1.x += x1 * wv.x; acc1.y += x1 * wv.y; acc1.z += x1 * wv.z; acc1.w += x1 * wv.w;
        acc2.x += x2 * wv.x; acc2.y += x2 * wv.y; acc2.z += x2 * wv.z; acc2.w += x2 * wv.w;
        acc3.x += x3 * wv.x; acc3.y += x3 * wv.y; acc3.z += x3 * wv.z; acc3.w += x3 * wv.w;
    }
    float4* h4 = (float4*)(h + row0 * CH);
    h4[(rg)      * 32 + ch4] = acc0;
    h4[(rg + 8)  * 32 + ch4] = acc1;
    h4[(rg + 16) * 32 + ch4] = acc2;
    h4[(rg + 24) * 32 + ch4] = acc3;
}

// one wave per node: out[n] = dinv[n]*Σ_in dinv[s]*h[s] + dinv[n]^2*h[n] + b
__global__ __launch_bounds__(256) void aggregate_kernel(const int* __restrict__ csr,
                                                        const int* __restrict__ offs,
                                                        const int* __restrict__ bases,
                                                        const float* __restrict__ h,
                                                        const float* __restrict__ dinv,
                                                        const float* __restrict__ b,
                                                        float* __restrict__ out) {
    int n = (blockIdx.x * blockDim.x + threadIdx.x) >> 6;
    int lane = threadIdx.x & 63;
    if (n >= N_NODES) return;
    int end = bases[n >> 8] + offs[n];
    int beg = (n == 0) ? 0 : (bases[(n - 1) >> 8] + offs[n - 1]);
    float dn = dinv[n];
    const float2* h2 = (const float2*)h;
    float2 acc = {0.0f, 0.0f};
    for (int j = beg; j < end; ++j) {
        int s = csr[j];
        float ds = dinv[s];
        float2 hv = h2[(size_t)s * 64 + lane];
        acc.x += hv.x * ds;
        acc.y += hv.y * ds;
    }
    float2 hn = h2[(size_t)n * 64 + lane];
    float2 bv = ((const float2*)b)[lane];
    float2 o;
    o.x = acc.x * dn + hn.x * dn * dn + bv.x;
    o.y = acc.y * dn + hn.y * dn * dn + bv.y;
    ((float2*)out)[(size_t)n * 64 + lane] = o;
}

#define STAT_BLOCKS 512
__global__ __launch_bounds__(256) void bn_stats_kernel(const float* __restrict__ out,
                                                       float* __restrict__ sums) {
    int t = threadIdx.x;
    int ch = t & (CH - 1);
    int half = t >> 7;
    float s = 0.0f, sq = 0.0f;
    for (int row = blockIdx.x * 2 + half; row < N_NODES; row += gridDim.x * 2) {
        float v = out[(size_t)row * CH + ch];
        s += v;
        sq += v * v;
    }
    __shared__ float ls[256], lq[256];
    ls[t] = s;
    lq[t] = sq;
    __syncthreads();
    if (half == 0) {
        s += ls[t + 128];
        sq += lq[t + 128];
        atomicAdd(&sums[ch], s);
        atomicAdd(&sums[CH + ch], sq);
    }
}

__global__ __launch_bounds__(256) void bn_relu_kernel(float* __restrict__ out,
                                                      const float* __restrict__ sums,
                                                      const float* __restrict__ gamma,
                                                      const float* __restrict__ beta) {
    int i = blockIdx.x * blockDim.x + threadIdx.x;
    if (i >= N_NODES * CH / 4) return;
    int c0 = (i & 31) * 4;
    const float invN = 1.0f / (float)N_NODES;
    float4 v = ((float4*)out)[i];
    float r[4] = {v.x, v.y, v.z, v.w};
#pragma unroll
    for (int j = 0; j < 4; ++j) {
        int c = c0 + j;
        float mean = sums[c] * invN;
        float var = sums[CH + c] * invN - mean * mean;
        float scale = gamma[c] * rsqrtf(var + BN_EPS);
        float val = (r[j] - mean) * scale + beta[c];
        r[j] = val > 0.0f ? val : 0.0f;
    }
    v.x = r[0]; v.y = r[1]; v.z = r[2]; v.w = r[3];
    ((float4*)out)[i] = v;
}

// ---------- fallback (round-1 scatter path) ----------
__global__ __launch_bounds__(256) void dinv_inplace_kernel(float* __restrict__ d) {
    int i = blockIdx.x * blockDim.x + threadIdx.x;
    if (i < N_NODES) d[i] = rsqrtf((float)((int*)d)[i] + 1.0f);
}

__global__ __launch_bounds__(256) void init_out_kernel(const float* __restrict__ h,
                                                       const float* __restrict__ dinv,
                                                       const float* __restrict__ b,
                                                       float* __restrict__ out) {
    int i = blockIdx.x * blockDim.x + threadIdx.x;
    if (i >= N_NODES * CH / 4) return;
    int row = i >> 5;
    int c4 = i & 31;
    float d = dinv[row];
    float s = d * d;
    float4 hv = ((const float4*)h)[i];
    float4 bv = ((const float4*)b)[c4];
    float4 o;
    o.x = hv.x * s + bv.x;
    o.y = hv.y * s + bv.y;
    o.z = hv.z * s + bv.z;
    o.w = hv.w * s + bv.w;
    ((float4*)out)[i] = o;
}

__global__ __launch_bounds__(256) void scatter_kernel(const int* __restrict__ src,
                                                      const int* __restrict__ dst,
                                                      const float* __restrict__ h,
                                                      const float* __restrict__ dinv,
                                                      float* __restrict__ out) {
    int wave = (blockIdx.x * blockDim.x + threadIdx.x) >> 6;
    int lane = threadIdx.x & 63;
    if (wave >= N_EDGES) return;
    int s = src[wave];
    int d = dst[wave];
    float norm = dinv[s] * dinv[d];
    const float* hs = h + (size_t)s * CH;
    float* od = out + (size_t)d * CH;
    atomicAdd(&od[lane], hs[lane] * norm);
    atomicAdd(&od[lane + 64], hs[lane + 64] * norm);
}

extern "C" void kernel_launch(void* const* d_in, const int* in_sizes, int n_in,
                              void* d_out, int out_size, void* d_ws, size_t ws_size,
                              hipStream_t stream) {
    const float* x = (const float*)d_in[0];
    const int* ei = (const int*)d_in[1];
    const float* W = (const float*)d_in[2];
    const float* b = (const float*)d_in[3];
    const float* gamma = (const float*)d_in[4];
    const float* beta = (const float*)d_in[5];
    float* out = (float*)d_out;
    const int* src = ei;
    const int* dst = ei + N_EDGES;
    char* ws = (char*)d_ws;

    if (ws_size >= FAST_WS_BYTES) {
        float* h = (float*)ws;
        int* deg = (int*)(ws + 20480000);
        float* sums = (float*)(ws + 20640000);
        int* offs = (int*)(ws + 20641024);
        float* dinv = (float*)(ws + 20801024);
        int* bases = (int*)(ws + 20961024);
        int* csr = (int*)(ws + 20961664);

        zero_kernel<<<(40256 + 255) / 256, 256, 0, stream>>>(deg, 40256);  // deg + sums
        deg_kernel<<<(N_EDGES + 255) / 256, 256, 0, stream>>>(dst, deg);
        dinv_kernel<<<(N_NODES + 255) / 256, 256, 0, stream>>>(deg, dinv);
        scan_a<<<NBLK_SCAN, 256, 0, stream>>>(deg, offs, bases);
        scan_b<<<1, 256, 0, stream>>>(bases);
        fill_kernel<<<(N_EDGES + 255) / 256, 256, 0, stream>>>(src, dst, bases, offs, csr);
        matmul_kernel<<<N_NODES / MM_ROWS, 256, 0, stream>>>(x, W, h);
        aggregate_kernel<<<(N_NODES * 64 + 255) / 256, 256, 0, stream>>>(csr, offs, bases, h,
                                                                         dinv, b, out);
        bn_stats_kernel<<<STAT_BLOCKS, 256, 0, stream>>>(out, sums);
        bn_relu_kernel<<<(N_NODES * CH / 4 + 255) / 256, 256, 0, stream>>>(out, sums, gamma, beta);
    } else {
        float* h = (float*)ws;
        float* dinv = (float*)(ws + 20480000);
        float* sums = (float*)(ws + 20640000);

        zero_kernel<<<(40256 + 255) / 256, 256, 0, stream>>>((int*)dinv, 40256);
        deg_kernel<<<(N_EDGES + 255) / 256, 256, 0, stream>>>(dst, (int*)dinv);
        dinv_inplace_kernel<<<(N_NODES + 255) / 256, 256, 0, stream>>>(dinv);
        matmul_kernel<<<N_NODES / MM_ROWS, 256, 0, stream>>>(x, W, h);
        init_out_kernel<<<(N_NODES * CH / 4 + 255) / 256, 256, 0, stream>>>(h, dinv, b, out);
        scatter_kernel<<<(N_EDGES * 64) / 256, 256, 0, stream>>>(src, dst, h, dinv, out);
        bn_stats_kernel<<<STAT_BLOCKS, 256, 0, stream>>>(out, sums);
        bn_relu_kernel<<<(N_NODES * CH / 4 + 255) / 256, 256, 0, stream>>>(out, sums, gamma, beta);
    }
}